// Round 16
// baseline (30.408 us; speedup 1.0000x reference)
//
#include <hip/hip_runtime.h>
#include <hip/hip_bf16.h>

typedef __bf16 bf16x8 __attribute__((ext_vector_type(8)));
typedef float  f32x4  __attribute__((ext_vector_type(4)));
typedef long   long2v __attribute__((ext_vector_type(2)));

#define UBV   35.0f
#define SUMC  150.0f

__device__ __forceinline__ float lrelu(float x) { return fmaxf(x, 0.2f * x); }

// one 32-bit word of 4 fp8(e4m3): 2 cvt_pk ops (bit-identical to pk8|pk8<<16)
__device__ __forceinline__ unsigned pkword(float a, float b, float c, float d) {
    unsigned w = (unsigned)__builtin_amdgcn_cvt_pk_fp8_f32(a, b, 0, false);
    w = (unsigned)__builtin_amdgcn_cvt_pk_fp8_f32(c, d, (int)w, true);
    return w;
}
__device__ __forceinline__ long mk64(unsigned lo, unsigned hi) {
    return (long)(((unsigned long long)hi << 32) | (unsigned long long)lo);
}
__device__ __forceinline__ void async16(void* lds_uniform, const void* gsrc) {
    __builtin_amdgcn_global_load_lds(
        (__attribute__((address_space(1))) void*)(gsrc),
        (__attribute__((address_space(3))) void*)(lds_uniform),
        16, 0, 0);
}

// ---------------------------------------------------------------------------
// prep: byte-identical to R15 (sigma mapping verified since R4; R15 paired-kt
// b128 layout per (q,t) 6656B block).
// ---------------------------------------------------------------------------

__global__ void prep_kernel(const float* __restrict__ W1, const float* __restrict__ b1,
                            const float* __restrict__ W2, const float* __restrict__ b2,
                            const float* __restrict__ W3, const float* __restrict__ b3,
                            __bf16* __restrict__ w1p, uint2* __restrict__ w2p,
                            uint2* __restrict__ w3c)
{
    int idx = blockIdx.x * blockDim.x + threadIdx.x;
    if (idx < 1664) {
        int lane = idx & 63;
        int nt = idx >> 6;
        int c16 = lane & 15, g = lane >> 4;
        int kk = nt >> 1, hh = nt & 1;
        int kap = kk * 32 + (c16 >> 2) * 8 + hh * 4 + (c16 & 3);
        bf16x8 v;
        #pragma unroll
        for (int j = 0; j < 8; ++j) {
            int k = g * 8 + j;
            float x = 0.f;
            if (kap < 400) {
                if (k < 17) x = W1[kap * 17 + k];
                else if (k == 17) x = b1[kap];
            } else if (kap == 400) {
                if (k == 17) x = 1.0f;
            }
            v[j] = (__bf16)x;
        }
        *(bf16x8*)(w1p + idx * 8) = v;
    } else if (idx < 1664 + 16640) {
        int i2 = idx - 1664;
        int fg = i2 >> 6, lane = i2 & 63;
        int q = fg / 65, rem = fg % 65;
        int t = rem / 13, kt = rem % 13;
        int c16 = lane & 15, g = lane >> 4;
        int local = t * 16 + c16;
        int ff = q * 79 + local;
        float v[8];
        #pragma unroll
        for (int j = 0; j < 8; ++j) {
            int kap = kt * 32 + g * 8 + j;
            float x = 0.f;
            if (local == 79) {
                x = (kap == 400) ? 1.0f : 0.f;
            } else if (local < 79 && ff < 300) {
                if (kap < 400) x = W2[ff * 400 + kap];
                else if (kap == 400) x = b2[ff];
            }
            v[j] = x;
        }
        uint2 d;
        d.x = pkword(v[0], v[1], v[2], v[3]);
        d.y = pkword(v[4], v[5], v[6], v[7]);
        int within = (kt < 12) ? ((kt >> 1) * 128 + lane * 2 + (kt & 1))
                               : (768 + lane);
        w2p[(q * 5 + t) * 832 + within] = d;
    } else if (idx < 1664 + 16640 + 768) {
        int i3 = idx - 1664 - 16640;
        int fg = i3 >> 6, lane = i3 & 63;
        int q = fg / 3, k2 = fg % 3;
        int o = lane & 15, g = lane >> 4;
        float v[8];
        #pragma unroll
        for (int j = 0; j < 8; ++j) {
            int t2  = 2 * k2 + (j >> 2);
            int rho = g * 4 + (j & 3);
            int local = t2 * 16 + rho;
            float x = 0.f;
            if (o < 5 && t2 < 5) {
                if (local == 79) x = b3[o] * 0.25f;
                else if (local < 79 && q * 79 + local < 300)
                    x = W3[o * 300 + q * 79 + local];
            }
            v[j] = x;
        }
        uint2 d;
        d.x = pkword(v[0], v[1], v[2], v[3]);
        d.y = pkword(v[4], v[5], v[6], v[7]);
        w3c[i3] = d;
    }
}

// ---------------------------------------------------------------------------
// Actor R16: 512 blocks x 512 threads (8 waves) = 128 rows/block.
// Wave (rg, qh): rg = wid&3 -> rows rg*32..+31 (dual m-tile, R15 inner loop);
// qh = wid>>2 -> quarters {2qh, 2qh+1} only. Doubles wave count (4096) ->
// 16 waves/CU = 4 waves/SIMD (R14 diagnosis: ~50% stall at 2 waves/SIMD;
// VALUBusy includes MFMA issue, true issue ~10.5us of 22us busy).
// Partial ccs summed across qh-halves via s_red; phase A duplicated per half
// (+8.7% MFMA); W1p read from L2 (no LDS); per half one 33.8KB quarter
// buffer, second-stage issued under the w3-fold. 4 barriers.
// ---------------------------------------------------------------------------
__global__ __launch_bounds__(512, 4)
void actor_kernel(const float* __restrict__ state,
                  const __bf16* __restrict__ w1p,
                  const uint2* __restrict__ w2p,
                  const uint2* __restrict__ w3c,
                  float* __restrict__ out)
{
    __shared__ __align__(16) char s_buf[2][33792];   // [qh] quarter buffer
    __shared__ float s_red[2][4][32][8];             // [qh][rg][row][o] 8KB

    const int tid = threadIdx.x;
    const int wid = tid >> 6;
    const int ln  = tid & 63;
    const int g   = ln >> 4, c16 = ln & 15;
    const int rg  = wid & 3;
    const int qh  = wid >> 2;
    const int brow = (blockIdx.x << 7) + rg * 32;

    // ---- stage first quarters: buf[b] <- quarter 2b (all 8 waves help) ----
    for (int b = 0; b < 2; ++b) {
        const char* gb = (const char*)w2p + (b * 2) * 33280;
        for (int i = wid; i < 33; i += 8)
            async16(&s_buf[b][0] + i * 1024, gb + i * 1024 + ln * 16);
    }

    // ---- state A-frags for the wave's two m-tiles ----
    bf16x8 sbA, sbB;
    {
        const float* spA = state + (brow + c16) * 17;
        const float* spB = spA + 16 * 17;
        if (g == 0) {
            #pragma unroll
            for (int j = 0; j < 8; ++j) { sbA[j] = (__bf16)spA[j]; sbB[j] = (__bf16)spB[j]; }
        } else if (g == 1) {
            #pragma unroll
            for (int j = 0; j < 8; ++j) { sbA[j] = (__bf16)spA[8 + j]; sbB[j] = (__bf16)spB[8 + j]; }
        } else if (g == 2) {
            sbA[0] = (__bf16)spA[16]; sbB[0] = (__bf16)spB[16];
            sbA[1] = (__bf16)1.0f;    sbB[1] = (__bf16)1.0f;   // bias carrier k=17
            #pragma unroll
            for (int j = 2; j < 8; ++j) { sbA[j] = (__bf16)0.f; sbB[j] = (__bf16)0.f; }
        } else {
            #pragma unroll
            for (int j = 0; j < 8; ++j) { sbA[j] = (__bf16)0.f; sbB[j] = (__bf16)0.f; }
        }
    }

    // ---- w3 frags for this half's 2 quarters (6 longs) ----
    long w3r[2][3];
    {
        const long* gw3 = (const long*)w3c;
        #pragma unroll
        for (int qi = 0; qi < 2; ++qi)
            #pragma unroll
            for (int k2 = 0; k2 < 3; ++k2)
                w3r[qi][k2] = gw3[((qh * 2 + qi) * 3 + k2) * 64 + ln];
    }

    // ---- Phase A from L2-resident w1p (no LDS round-trip) ----
    long frvA[13], frvB[13];
    #pragma unroll
    for (int kt = 0; kt < 13; ++kt) {
        bf16x8 we = *(const bf16x8*)(w1p + ((2 * kt) * 64 + ln) * 8);
        bf16x8 wo = *(const bf16x8*)(w1p + ((2 * kt + 1) * 64 + ln) * 8);
        f32x4 aeA = {0.f,0.f,0.f,0.f}, aoA = {0.f,0.f,0.f,0.f};
        f32x4 aeB = {0.f,0.f,0.f,0.f}, aoB = {0.f,0.f,0.f,0.f};
        aeA = __builtin_amdgcn_mfma_f32_16x16x32_bf16(we, sbA, aeA, 0, 0, 0);
        aoA = __builtin_amdgcn_mfma_f32_16x16x32_bf16(wo, sbA, aoA, 0, 0, 0);
        aeB = __builtin_amdgcn_mfma_f32_16x16x32_bf16(we, sbB, aeB, 0, 0, 0);
        aoB = __builtin_amdgcn_mfma_f32_16x16x32_bf16(wo, sbB, aoB, 0, 0, 0);
        frvA[kt] = mk64(
            pkword(lrelu(aeA[0]), lrelu(aeA[1]), lrelu(aeA[2]), lrelu(aeA[3])),
            pkword(lrelu(aoA[0]), lrelu(aoA[1]), lrelu(aoA[2]), lrelu(aoA[3])));
        frvB[kt] = mk64(
            pkword(lrelu(aeB[0]), lrelu(aeB[1]), lrelu(aeB[2]), lrelu(aeB[3])),
            pkword(lrelu(aoB[0]), lrelu(aoB[1]), lrelu(aoB[2]), lrelu(aoB[3])));
    }

    __syncthreads();   // B1: first quarters staged

    // ---- consume one quarter from s_buf[qh]: R15 inner loop -> wd words ----
    unsigned wdA[5], wdB[5];
    auto consume_q = [&]() {
        const char* bufp = &s_buf[qh][0];
        #pragma unroll
        for (int t = 0; t < 5; ++t) {
            const char* bt = bufp + t * 6656;
            f32x4 aA = {0.f,0.f,0.f,0.f}, aB = {0.f,0.f,0.f,0.f};
            #pragma unroll
            for (int kt2 = 0; kt2 < 6; ++kt2) {
                long2v p = *(const long2v*)(bt + kt2 * 1024 + ln * 16);
                aA = __builtin_amdgcn_mfma_f32_16x16x32_fp8_fp8(p[0], frvA[2 * kt2],     aA, 0, 0, 0);
                aB = __builtin_amdgcn_mfma_f32_16x16x32_fp8_fp8(p[0], frvB[2 * kt2],     aB, 0, 0, 0);
                aA = __builtin_amdgcn_mfma_f32_16x16x32_fp8_fp8(p[1], frvA[2 * kt2 + 1], aA, 0, 0, 0);
                aB = __builtin_amdgcn_mfma_f32_16x16x32_fp8_fp8(p[1], frvB[2 * kt2 + 1], aB, 0, 0, 0);
            }
            long p12 = *(const long*)(bt + 6144 + ln * 8);
            aA = __builtin_amdgcn_mfma_f32_16x16x32_fp8_fp8(p12, frvA[12], aA, 0, 0, 0);
            aB = __builtin_amdgcn_mfma_f32_16x16x32_fp8_fp8(p12, frvB[12], aB, 0, 0, 0);
            wdA[t] = pkword(lrelu(aA[0]), lrelu(aA[1]), lrelu(aA[2]), lrelu(aA[3]));
            wdB[t] = pkword(lrelu(aB[0]), lrelu(aB[1]), lrelu(aB[2]), lrelu(aB[3]));
        }
    };
    auto fold_q = [&](int qi, f32x4& cA, f32x4& cB) {
        f32x4 cc = {0.f, 0.f, 0.f, 0.f};
        cc = __builtin_amdgcn_mfma_f32_16x16x32_fp8_fp8(w3r[qi][0], mk64(wdA[0], wdA[1]), cc, 0, 0, 0);
        cc = __builtin_amdgcn_mfma_f32_16x16x32_fp8_fp8(w3r[qi][1], mk64(wdA[2], wdA[3]), cc, 0, 0, 0);
        cc = __builtin_amdgcn_mfma_f32_16x16x32_fp8_fp8(w3r[qi][2], mk64(wdA[4], 0u),     cc, 0, 0, 0);
        cA += cc;
        f32x4 cd = {0.f, 0.f, 0.f, 0.f};
        cd = __builtin_amdgcn_mfma_f32_16x16x32_fp8_fp8(w3r[qi][0], mk64(wdB[0], wdB[1]), cd, 0, 0, 0);
        cd = __builtin_amdgcn_mfma_f32_16x16x32_fp8_fp8(w3r[qi][1], mk64(wdB[2], wdB[3]), cd, 0, 0, 0);
        cd = __builtin_amdgcn_mfma_f32_16x16x32_fp8_fp8(w3r[qi][2], mk64(wdB[4], 0u),     cd, 0, 0, 0);
        cB += cd;
    };

    f32x4 ccsA = {0.f, 0.f, 0.f, 0.f};
    f32x4 ccsB = {0.f, 0.f, 0.f, 0.f};

    // ---- quarter 2qh ----
    consume_q();
    __syncthreads();   // B2: all buffer reads done -> safe to restage

    // issue second-stage: buf[b] <- quarter 2b+1; fold1 runs under it
    for (int b = 0; b < 2; ++b) {
        const char* gb = (const char*)w2p + (b * 2 + 1) * 33280;
        for (int i = wid; i < 33; i += 8)
            async16(&s_buf[b][0] + i * 1024, gb + i * 1024 + ln * 16);
    }
    fold_q(0, ccsA, ccsB);

    __syncthreads();   // B3: second quarters staged

    // ---- quarter 2qh+1 ----
    consume_q();
    fold_q(1, ccsA, ccsB);

    // ---- publish partial sums: [qh][rg][row][o] ----
    if (g == 0) {
        #pragma unroll
        for (int o = 0; o < 4; ++o) {
            s_red[qh][rg][c16][o]      = ccsA[o];
            s_red[qh][rg][16 + c16][o] = ccsB[o];
        }
    } else if (g == 1) {
        s_red[qh][rg][c16][4]      = ccsA[0];
        s_red[qh][rg][16 + c16][4] = ccsB[0];
    }
    __syncthreads();   // B4: partials visible

    // ---- Epilogue: qh==0 waves solve QP for their rg's 32 rows ----
    if (qh == 0 && ln < 32) {
        float v[5];
        #pragma unroll
        for (int o = 0; o < 5; ++o) {
            float s = s_red[0][rg][ln][o] + s_red[1][rg][ln][o];
            v[o] = -lrelu(s);
        }

        float bp[10];
        #pragma unroll
        for (int i = 0; i < 5; ++i) { bp[i] = v[i]; bp[i + 5] = v[i] - UBV; }
        float blo = -1e30f, glo = 0.f;
        #pragma unroll
        for (int j = 0; j < 10; ++j) {
            float b = bp[j];
            float gsum = 0.f;
            #pragma unroll
            for (int i = 0; i < 5; ++i) {
                float zc = v[i] - b;
                zc = fminf(fmaxf(zc, 0.f), UBV);
                gsum += zc;
            }
            if (gsum >= SUMC && b > blo) { blo = b; glo = gsum; }
        }
        float bhi = 1e30f;
        #pragma unroll
        for (int j = 0; j < 10; ++j) {
            float b = bp[j];
            if (b > blo && b < bhi) bhi = b;
        }
        float mid = 0.5f * (blo + bhi);
        int nfree = 0;
        #pragma unroll
        for (int i = 0; i < 5; ++i)
            nfree += (v[i] > mid && v[i] < mid + UBV) ? 1 : 0;
        float nu = (nfree > 0) ? blo + (glo - SUMC) / (float)nfree : blo;

        int row = brow + ln;
        #pragma unroll
        for (int o = 0; o < 5; ++o) {
            float zf = v[o] - nu;
            zf = fminf(fmaxf(zf, 0.f), UBV);
            out[row * 5 + o] = zf;
        }
    }
}

extern "C" void kernel_launch(void* const* d_in, const int* in_sizes, int n_in,
                              void* d_out, int out_size, void* d_ws, size_t ws_size,
                              hipStream_t stream) {
    const float* state = (const float*)d_in[0];
    const float* W1    = (const float*)d_in[1];
    const float* b1    = (const float*)d_in[2];
    const float* W2    = (const float*)d_in[3];
    const float* b2    = (const float*)d_in[4];
    const float* W3    = (const float*)d_in[5];
    const float* b3    = (const float*)d_in[6];
    float* out = (float*)d_out;

    char* base = (char*)d_ws;
    __bf16* w1p = (__bf16*)base;                   // 26,624B
    uint2*  w2p = (uint2*)(base + 26624);          // 133,120B
    uint2*  w3c = (uint2*)(base + 26624 + 133120); // 6,144B (q3 tail overread lands here -- harmless)

    const int total = 1664 + 16640 + 768;
    prep_kernel<<<(total + 255) / 256, 256, 0, stream>>>(W1, b1, W2, b2, W3, b3,
                                                         w1p, w2p, w3c);

    int B = in_sizes[0] / 17;                      // 65536
    actor_kernel<<<B / 128, 512, 0, stream>>>(state, w1p, w2p, w3c, out);
}

// Round 17
// 26.671 us; speedup vs baseline: 1.1401x; 1.1401x over previous
//
#include <hip/hip_runtime.h>
#include <hip/hip_bf16.h>

typedef __bf16 bf16x8 __attribute__((ext_vector_type(8)));
typedef float  f32x4  __attribute__((ext_vector_type(4)));
typedef long   long2v __attribute__((ext_vector_type(2)));
typedef int    int8v  __attribute__((ext_vector_type(8)));

#define UBV   35.0f
#define SUMC  150.0f
#define SCL1  0x7f7f7f7f   // 4x e8m0 scale = 1.0 (2^(127-127)) per 32-elem block

__device__ __forceinline__ float lrelu(float x) { return fmaxf(x, 0.2f * x); }

// one 32-bit word of 4 fp8(e4m3): 2 cvt_pk ops
__device__ __forceinline__ unsigned pkword(float a, float b, float c, float d) {
    unsigned w = (unsigned)__builtin_amdgcn_cvt_pk_fp8_f32(a, b, 0, false);
    w = (unsigned)__builtin_amdgcn_cvt_pk_fp8_f32(c, d, (int)w, true);
    return w;
}
__device__ __forceinline__ long mk64(unsigned lo, unsigned hi) {
    return (long)(((unsigned long long)hi << 32) | (unsigned long long)lo);
}
__device__ __forceinline__ void async16(void* lds_uniform, const void* gsrc) {
    __builtin_amdgcn_global_load_lds(
        (__attribute__((address_space(1))) void*)(gsrc),
        (__attribute__((address_space(3))) void*)(lds_uniform),
        16, 0, 0);
}

// ---------------------------------------------------------------------------
// R17 sigma mapping (K=128 MX layer 2):
//   h1 slots 0..383 feed three K=128 MX blocks m=0..2; lane (g,c16) of the
//   B-fragment holds k = 128m + 32g + {0..31}; phase-A tile nt (<24) yields
//   dword j=nt&7 of block m=nt>>3:  kappa(nt,rho) = 128(nt>>3)+32(rho>>2)
//   +4(nt&7)+(rho&3).  Slots 384..415 (incl. bias carrier 400) stay on the
//   verified K=32 fp8 tail path: tiles 24,25, kappa = 384+8(rho>>2)+4(nt&1)
//   +(rho&3).  W2 chunks per (q,t): 3x2048B MX (lane*32B, k=128m+32g+b) +
//   512B tail (old layout) = 6656B (same staging geometry as R15).
// ---------------------------------------------------------------------------

__global__ void prep_kernel(const float* __restrict__ W1, const float* __restrict__ b1,
                            const float* __restrict__ W2, const float* __restrict__ b2,
                            const float* __restrict__ W3, const float* __restrict__ b3,
                            __bf16* __restrict__ w1p, uint2* __restrict__ w2p,
                            uint2* __restrict__ w3c)
{
    int idx = blockIdx.x * blockDim.x + threadIdx.x;
    if (idx < 1664) {
        int lane = idx & 63;
        int nt = idx >> 6;
        int rho = lane & 15, g = lane >> 4;
        int kap = (nt < 24)
            ? 128 * (nt >> 3) + 32 * (rho >> 2) + 4 * (nt & 7) + (rho & 3)
            : 384 + 8 * (rho >> 2) + 4 * (nt & 1) + (rho & 3);
        bf16x8 v;
        #pragma unroll
        for (int j = 0; j < 8; ++j) {
            int k = g * 8 + j;
            float x = 0.f;
            if (kap < 400) {
                if (k < 17) x = W1[kap * 17 + k];
                else if (k == 17) x = b1[kap];
            } else if (kap == 400) {
                if (k == 17) x = 1.0f;
            }
            v[j] = (__bf16)x;
        }
        *(bf16x8*)(w1p + idx * 8) = v;
    } else if (idx < 1664 + 16640) {
        int i2 = idx - 1664;
        int fg = i2 >> 6, lane = i2 & 63;
        int q = fg / 65, rem = fg % 65;
        int t = rem / 13, kt = rem % 13;
        int c16 = lane & 15, g = lane >> 4;
        int local = t * 16 + c16;
        int ff = q * 79 + local;
        int within, kbase;
        if (kt < 12) {                      // MX chunk m, uint2 u within lane's 32B
            int m = kt >> 2, u = kt & 3;
            kbase = 128 * m + 32 * g + 8 * u;
            within = m * 256 + lane * 4 + u;
        } else {                            // K=32 tail (old layout, kappa 384..415)
            kbase = 384 + g * 8;
            within = 768 + lane;
        }
        float v[8];
        #pragma unroll
        for (int j = 0; j < 8; ++j) {
            int kap = kbase + j;
            float x = 0.f;
            if (local == 79) {
                x = (kap == 400) ? 1.0f : 0.f;
            } else if (local < 79 && ff < 300) {
                if (kap < 400) x = W2[ff * 400 + kap];
                else if (kap == 400) x = b2[ff];
            }
            v[j] = x;
        }
        uint2 d;
        d.x = pkword(v[0], v[1], v[2], v[3]);
        d.y = pkword(v[4], v[5], v[6], v[7]);
        w2p[(q * 5 + t) * 832 + within] = d;
    } else if (idx < 1664 + 16640 + 768) {
        int i3 = idx - 1664 - 16640;
        int fg = i3 >> 6, lane = i3 & 63;
        int q = fg / 3, k2 = fg % 3;
        int o = lane & 15, g = lane >> 4;
        float v[8];
        #pragma unroll
        for (int j = 0; j < 8; ++j) {
            int t2  = 2 * k2 + (j >> 2);
            int rho = g * 4 + (j & 3);
            int local = t2 * 16 + rho;
            float x = 0.f;
            if (o < 5 && t2 < 5) {
                if (local == 79) x = b3[o] * 0.25f;
                else if (local < 79 && q * 79 + local < 300)
                    x = W3[o * 300 + q * 79 + local];
            }
            v[j] = x;
        }
        uint2 d;
        d.x = pkword(v[0], v[1], v[2], v[3]);
        d.y = pkword(v[4], v[5], v[6], v[7]);
        w3c[i3] = d;
    }
}

// ---------------------------------------------------------------------------
// Actor R17: R15 geometry (512 x 256thr, 4 waves, dual m-tile/wave, double-
// buffered quarters, 2 blocks/CU) with layer 2 on mfma_scale K=128 MX
// (unit scales): per (q,t) 3 MX + 1 K=32 tail MFMA per batch-tile.
// MFMA/wave 596 -> ~330 issue-equivalents; floor 9.7 -> ~5.3us. Phase A
// emits MX B-fragments directly via the re-derived sigma (no extra work).
// ---------------------------------------------------------------------------
__global__ __launch_bounds__(256, 1)
void actor_kernel(const float* __restrict__ state,
                  const __bf16* __restrict__ w1p,
                  const uint2* __restrict__ w2p,
                  const uint2* __restrict__ w3c,
                  float* __restrict__ out)
{
    __shared__ __align__(32) char s_mem[2][33792];   // 67,584B double buffer

    const int tid = threadIdx.x;
    const int wid = tid >> 6;
    const int ln  = tid & 63;
    const int g   = ln >> 4, c16 = ln & 15;
    const int brow = blockIdx.x << 7;    // 128 rows/block

    // ---- stage W1p -> buf0 AND quarter q0 -> buf1 ----
    {
        const char* gb1 = (const char*)w1p;
        #pragma unroll
        for (int i = wid; i < 26; i += 4)
            async16(&s_mem[0][0] + i * 1024, gb1 + i * 1024 + ln * 16);
        const char* gb2 = (const char*)w2p;
        #pragma unroll
        for (int i = wid; i < 33; i += 4)
            async16(&s_mem[1][0] + i * 1024, gb2 + i * 1024 + ln * 16);
    }

    // ---- state A-frags for both m-tiles ----
    bf16x8 sbA, sbB;
    {
        const float* spA = state + (brow + wid * 32 + c16) * 17;
        const float* spB = spA + 16 * 17;
        if (g == 0) {
            #pragma unroll
            for (int j = 0; j < 8; ++j) { sbA[j] = (__bf16)spA[j]; sbB[j] = (__bf16)spB[j]; }
        } else if (g == 1) {
            #pragma unroll
            for (int j = 0; j < 8; ++j) { sbA[j] = (__bf16)spA[8 + j]; sbB[j] = (__bf16)spB[8 + j]; }
        } else if (g == 2) {
            sbA[0] = (__bf16)spA[16]; sbB[0] = (__bf16)spB[16];
            sbA[1] = (__bf16)1.0f;    sbB[1] = (__bf16)1.0f;   // bias carrier k=17
            #pragma unroll
            for (int j = 2; j < 8; ++j) { sbA[j] = (__bf16)0.f; sbB[j] = (__bf16)0.f; }
        } else {
            #pragma unroll
            for (int j = 0; j < 8; ++j) { sbA[j] = (__bf16)0.f; sbB[j] = (__bf16)0.f; }
        }
    }

    // ---- hoisted W3 fragment loads ----
    long w3r[4][3];
    {
        const long* gw3 = (const long*)w3c;
        #pragma unroll
        for (int q = 0; q < 4; ++q)
            #pragma unroll
            for (int k2 = 0; k2 < 3; ++k2)
                w3r[q][k2] = gw3[(q * 3 + k2) * 64 + ln];
    }

    __syncthreads();   // W1 (buf0) and q0 (buf1) staged

    // ---- Phase A: h1 as MX B-fragments (3 int8v + 1 tail long per tile) ----
    int8v fmA[3], fmB[3];
    long fr12A, fr12B;
    {
        const __bf16* w1l = (const __bf16*)&s_mem[0][0];
        #pragma unroll
        for (int m = 0; m < 3; ++m)
            #pragma unroll
            for (int j = 0; j < 8; ++j) {
                int nt = m * 8 + j;
                bf16x8 w = *(const bf16x8*)(w1l + (nt * 64 + ln) * 8);
                f32x4 aA = {0.f,0.f,0.f,0.f}, aB = {0.f,0.f,0.f,0.f};
                aA = __builtin_amdgcn_mfma_f32_16x16x32_bf16(w, sbA, aA, 0, 0, 0);
                aB = __builtin_amdgcn_mfma_f32_16x16x32_bf16(w, sbB, aB, 0, 0, 0);
                fmA[m][j] = (int)pkword(lrelu(aA[0]), lrelu(aA[1]), lrelu(aA[2]), lrelu(aA[3]));
                fmB[m][j] = (int)pkword(lrelu(aB[0]), lrelu(aB[1]), lrelu(aB[2]), lrelu(aB[3]));
            }
        unsigned dA[2], dB[2];
        #pragma unroll
        for (int h = 0; h < 2; ++h) {
            int nt = 24 + h;
            bf16x8 w = *(const bf16x8*)(w1l + (nt * 64 + ln) * 8);
            f32x4 aA = {0.f,0.f,0.f,0.f}, aB = {0.f,0.f,0.f,0.f};
            aA = __builtin_amdgcn_mfma_f32_16x16x32_bf16(w, sbA, aA, 0, 0, 0);
            aB = __builtin_amdgcn_mfma_f32_16x16x32_bf16(w, sbB, aB, 0, 0, 0);
            dA[h] = pkword(lrelu(aA[0]), lrelu(aA[1]), lrelu(aA[2]), lrelu(aA[3]));
            dB[h] = pkword(lrelu(aB[0]), lrelu(aB[1]), lrelu(aB[2]), lrelu(aB[3]));
        }
        fr12A = mk64(dA[0], dA[1]);
        fr12B = mk64(dB[0], dB[1]);
    }

    __syncthreads();   // buf0 free for q1

    // ---- q-loop: consume buf[(q&1)^1]; stage q+1 into buf[q&1] ----
    f32x4 ccsA = {0.f, 0.f, 0.f, 0.f};
    f32x4 ccsB = {0.f, 0.f, 0.f, 0.f};

    #pragma unroll 1
    for (int q = 0; q < 4; ++q) {
        if (q < 3) {
            char* lb = &s_mem[q & 1][0];
            const char* gb = (const char*)w2p + (q + 1) * 33280;
            #pragma unroll
            for (int i = wid; i < 33; i += 4)
                async16(lb + i * 1024, gb + i * 1024 + ln * 16);
        }

        const char* bufp = &s_mem[(q & 1) ^ 1][0];
        unsigned wdA[5], wdB[5];
        #pragma unroll
        for (int t = 0; t < 5; ++t) {
            const char* bt = bufp + t * 6656;
            f32x4 aA = {0.f,0.f,0.f,0.f}, aB = {0.f,0.f,0.f,0.f};
            #pragma unroll
            for (int m = 0; m < 3; ++m) {
                int8v wf = *(const int8v*)(bt + m * 2048 + ln * 32);
                aA = __builtin_amdgcn_mfma_scale_f32_16x16x128_f8f6f4(
                         wf, fmA[m], aA, 0, 0, 0, SCL1, 0, SCL1);
                aB = __builtin_amdgcn_mfma_scale_f32_16x16x128_f8f6f4(
                         wf, fmB[m], aB, 0, 0, 0, SCL1, 0, SCL1);
            }
            long p12 = *(const long*)(bt + 6144 + ln * 8);
            aA = __builtin_amdgcn_mfma_f32_16x16x32_fp8_fp8(p12, fr12A, aA, 0, 0, 0);
            aB = __builtin_amdgcn_mfma_f32_16x16x32_fp8_fp8(p12, fr12B, aB, 0, 0, 0);
            wdA[t] = pkword(lrelu(aA[0]), lrelu(aA[1]), lrelu(aA[2]), lrelu(aA[3]));
            wdB[t] = pkword(lrelu(aB[0]), lrelu(aB[1]), lrelu(aB[2]), lrelu(aB[3]));
        }
        {
            f32x4 cc = {0.f, 0.f, 0.f, 0.f};
            cc = __builtin_amdgcn_mfma_f32_16x16x32_fp8_fp8(w3r[q][0], mk64(wdA[0], wdA[1]), cc, 0, 0, 0);
            cc = __builtin_amdgcn_mfma_f32_16x16x32_fp8_fp8(w3r[q][1], mk64(wdA[2], wdA[3]), cc, 0, 0, 0);
            cc = __builtin_amdgcn_mfma_f32_16x16x32_fp8_fp8(w3r[q][2], mk64(wdA[4], 0u),     cc, 0, 0, 0);
            ccsA += cc;
        }
        {
            f32x4 cc = {0.f, 0.f, 0.f, 0.f};
            cc = __builtin_amdgcn_mfma_f32_16x16x32_fp8_fp8(w3r[q][0], mk64(wdB[0], wdB[1]), cc, 0, 0, 0);
            cc = __builtin_amdgcn_mfma_f32_16x16x32_fp8_fp8(w3r[q][1], mk64(wdB[2], wdB[3]), cc, 0, 0, 0);
            cc = __builtin_amdgcn_mfma_f32_16x16x32_fp8_fp8(w3r[q][2], mk64(wdB[4], 0u),     cc, 0, 0, 0);
            ccsB += cc;
        }
        if (q < 3) __syncthreads();
    }

    // ---- Epilogue: 32 lanes/wave solve QP for 32 rows (R15 verbatim) ----
    float tA4 = __shfl_xor(ccsA[0], 16);
    float sB0 = __shfl_xor(ccsB[0], 16);
    float sB1 = __shfl_xor(ccsB[1], 16);
    float sB2 = __shfl_xor(ccsB[2], 16);
    float sB3 = __shfl_xor(ccsB[3], 16);

    if (ln < 32) {
        float v[5];
        if (ln < 16) {
            v[0] = -lrelu(ccsA[0]); v[1] = -lrelu(ccsA[1]);
            v[2] = -lrelu(ccsA[2]); v[3] = -lrelu(ccsA[3]);
            v[4] = -lrelu(tA4);
        } else {
            v[0] = -lrelu(sB0); v[1] = -lrelu(sB1);
            v[2] = -lrelu(sB2); v[3] = -lrelu(sB3);
            v[4] = -lrelu(ccsB[0]);
        }

        float bp[10];
        #pragma unroll
        for (int i = 0; i < 5; ++i) { bp[i] = v[i]; bp[i + 5] = v[i] - UBV; }
        float blo = -1e30f, glo = 0.f;
        #pragma unroll
        for (int j = 0; j < 10; ++j) {
            float b = bp[j];
            float gsum = 0.f;
            #pragma unroll
            for (int i = 0; i < 5; ++i) {
                float zc = v[i] - b;
                zc = fminf(fmaxf(zc, 0.f), UBV);
                gsum += zc;
            }
            if (gsum >= SUMC && b > blo) { blo = b; glo = gsum; }
        }
        float bhi = 1e30f;
        #pragma unroll
        for (int j = 0; j < 10; ++j) {
            float b = bp[j];
            if (b > blo && b < bhi) bhi = b;
        }
        float mid = 0.5f * (blo + bhi);
        int nfree = 0;
        #pragma unroll
        for (int i = 0; i < 5; ++i)
            nfree += (v[i] > mid && v[i] < mid + UBV) ? 1 : 0;
        float nu = (nfree > 0) ? blo + (glo - SUMC) / (float)nfree : blo;

        int row = brow + wid * 32 + ln;
        #pragma unroll
        for (int o = 0; o < 5; ++o) {
            float zf = v[o] - nu;
            zf = fminf(fmaxf(zf, 0.f), UBV);
            out[row * 5 + o] = zf;
        }
    }
}

extern "C" void kernel_launch(void* const* d_in, const int* in_sizes, int n_in,
                              void* d_out, int out_size, void* d_ws, size_t ws_size,
                              hipStream_t stream) {
    const float* state = (const float*)d_in[0];
    const float* W1    = (const float*)d_in[1];
    const float* b1    = (const float*)d_in[2];
    const float* W2    = (const float*)d_in[3];
    const float* b2    = (const float*)d_in[4];
    const float* W3    = (const float*)d_in[5];
    const float* b3    = (const float*)d_in[6];
    float* out = (float*)d_out;

    char* base = (char*)d_ws;
    __bf16* w1p = (__bf16*)base;                   // 26,624B
    uint2*  w2p = (uint2*)(base + 26624);          // 133,120B
    uint2*  w3c = (uint2*)(base + 26624 + 133120); // 6,144B

    const int total = 1664 + 16640 + 768;
    prep_kernel<<<(total + 255) / 256, 256, 0, stream>>>(W1, b1, W2, b2, W3, b3,
                                                         w1p, w2p, w3c);

    int B = in_sizes[0] / 17;                      // 65536
    actor_kernel<<<B / 128, 256, 0, stream>>>(state, w1p, w2p, w3c, out);
}

// Round 18
// 25.325 us; speedup vs baseline: 1.2007x; 1.0531x over previous
//
#include <hip/hip_runtime.h>
#include <hip/hip_bf16.h>

typedef __bf16 bf16x8 __attribute__((ext_vector_type(8)));
typedef float  f32x4  __attribute__((ext_vector_type(4)));
typedef int    int8v  __attribute__((ext_vector_type(8)));

#define UBV   35.0f
#define SUMC  150.0f
#define SCL1  0x7f7f7f7f   // 4x e8m0 scale = 1.0 per 32-elem block

__device__ __forceinline__ float lrelu(float x) { return fmaxf(x, 0.2f * x); }

__device__ __forceinline__ unsigned pkword(float a, float b, float c, float d) {
    unsigned w = (unsigned)__builtin_amdgcn_cvt_pk_fp8_f32(a, b, 0, false);
    w = (unsigned)__builtin_amdgcn_cvt_pk_fp8_f32(c, d, (int)w, true);
    return w;
}
__device__ __forceinline__ long mk64(unsigned lo, unsigned hi) {
    return (long)(((unsigned long long)hi << 32) | (unsigned long long)lo);
}
__device__ __forceinline__ void async16(void* lds_uniform, const void* gsrc) {
    __builtin_amdgcn_global_load_lds(
        (__attribute__((address_space(1))) void*)(gsrc),
        (__attribute__((address_space(3))) void*)(lds_uniform),
        16, 0, 0);
}

// ---------------------------------------------------------------------------
// prep: byte-identical to R17 (MX sigma mapping, verified absmax 0.125).
// ---------------------------------------------------------------------------

__global__ void prep_kernel(const float* __restrict__ W1, const float* __restrict__ b1,
                            const float* __restrict__ W2, const float* __restrict__ b2,
                            const float* __restrict__ W3, const float* __restrict__ b3,
                            __bf16* __restrict__ w1p, uint2* __restrict__ w2p,
                            uint2* __restrict__ w3c)
{
    int idx = blockIdx.x * blockDim.x + threadIdx.x;
    if (idx < 1664) {
        int lane = idx & 63;
        int nt = idx >> 6;
        int rho = lane & 15, g = lane >> 4;
        int kap = (nt < 24)
            ? 128 * (nt >> 3) + 32 * (rho >> 2) + 4 * (nt & 7) + (rho & 3)
            : 384 + 8 * (rho >> 2) + 4 * (nt & 1) + (rho & 3);
        bf16x8 v;
        #pragma unroll
        for (int j = 0; j < 8; ++j) {
            int k = g * 8 + j;
            float x = 0.f;
            if (kap < 400) {
                if (k < 17) x = W1[kap * 17 + k];
                else if (k == 17) x = b1[kap];
            } else if (kap == 400) {
                if (k == 17) x = 1.0f;
            }
            v[j] = (__bf16)x;
        }
        *(bf16x8*)(w1p + idx * 8) = v;
    } else if (idx < 1664 + 16640) {
        int i2 = idx - 1664;
        int fg = i2 >> 6, lane = i2 & 63;
        int q = fg / 65, rem = fg % 65;
        int t = rem / 13, kt = rem % 13;
        int c16 = lane & 15, g = lane >> 4;
        int local = t * 16 + c16;
        int ff = q * 79 + local;
        int within, kbase;
        if (kt < 12) {
            int m = kt >> 2, u = kt & 3;
            kbase = 128 * m + 32 * g + 8 * u;
            within = m * 256 + lane * 4 + u;
        } else {
            kbase = 384 + g * 8;
            within = 768 + lane;
        }
        float v[8];
        #pragma unroll
        for (int j = 0; j < 8; ++j) {
            int kap = kbase + j;
            float x = 0.f;
            if (local == 79) {
                x = (kap == 400) ? 1.0f : 0.f;
            } else if (local < 79 && ff < 300) {
                if (kap < 400) x = W2[ff * 400 + kap];
                else if (kap == 400) x = b2[ff];
            }
            v[j] = x;
        }
        uint2 d;
        d.x = pkword(v[0], v[1], v[2], v[3]);
        d.y = pkword(v[4], v[5], v[6], v[7]);
        w2p[(q * 5 + t) * 832 + within] = d;
    } else if (idx < 1664 + 16640 + 768) {
        int i3 = idx - 1664 - 16640;
        int fg = i3 >> 6, lane = i3 & 63;
        int q = fg / 3, k2 = fg % 3;
        int o = lane & 15, g = lane >> 4;
        float v[8];
        #pragma unroll
        for (int j = 0; j < 8; ++j) {
            int t2  = 2 * k2 + (j >> 2);
            int rho = g * 4 + (j & 3);
            int local = t2 * 16 + rho;
            float x = 0.f;
            if (o < 5 && t2 < 5) {
                if (local == 79) x = b3[o] * 0.25f;
                else if (local < 79 && q * 79 + local < 300)
                    x = W3[o * 300 + q * 79 + local];
            }
            v[j] = x;
        }
        uint2 d;
        d.x = pkword(v[0], v[1], v[2], v[3]);
        d.y = pkword(v[4], v[5], v[6], v[7]);
        w3c[i3] = d;
    }
}

// ---------------------------------------------------------------------------
// Actor R18: 256 blocks x 512 threads (8 waves, dual m-tile -> 256 rows),
// 1 block/CU. ALL of W2p (130KB) staged into LDS once (fits 160KB); phase A
// reads w1p straight from L2 (R16-validated); then ONE barrier and every
// wave runs its 4 quarters + fold + QP epilogue with no further syncs
// (LDS is read-only). Barriers 5 -> 1; wave stalls decorrelate; per-CU W2
// L2 traffic halves. Inner loop = R17's verified MX code (absmax 0.125).
// ---------------------------------------------------------------------------
__global__ __launch_bounds__(512, 2)
void actor_kernel(const float* __restrict__ state,
                  const __bf16* __restrict__ w1p,
                  const uint2* __restrict__ w2p,
                  const uint2* __restrict__ w3c,
                  float* __restrict__ out)
{
    __shared__ __align__(32) char s_w2[133120];   // entire W2p, read-only after B1

    const int tid = threadIdx.x;
    const int wid = tid >> 6;            // 8 waves: rows wid*32..+31
    const int ln  = tid & 63;
    const int g   = ln >> 4, c16 = ln & 15;
    const int brow = (blockIdx.x << 8) + wid * 32;   // 256 rows/block

    // ---- stage ALL W2p -> LDS (130 x 1KB chunks, 8-wave stride) ----
    {
        const char* gb = (const char*)w2p;
        for (int i = wid; i < 130; i += 8)
            async16(s_w2 + i * 1024, gb + i * 1024 + ln * 16);
    }

    // ---- state A-frags for both m-tiles ----
    bf16x8 sbA, sbB;
    {
        const float* spA = state + (brow + c16) * 17;
        const float* spB = spA + 16 * 17;
        if (g == 0) {
            #pragma unroll
            for (int j = 0; j < 8; ++j) { sbA[j] = (__bf16)spA[j]; sbB[j] = (__bf16)spB[j]; }
        } else if (g == 1) {
            #pragma unroll
            for (int j = 0; j < 8; ++j) { sbA[j] = (__bf16)spA[8 + j]; sbB[j] = (__bf16)spB[8 + j]; }
        } else if (g == 2) {
            sbA[0] = (__bf16)spA[16]; sbB[0] = (__bf16)spB[16];
            sbA[1] = (__bf16)1.0f;    sbB[1] = (__bf16)1.0f;   // bias carrier k=17
            #pragma unroll
            for (int j = 2; j < 8; ++j) { sbA[j] = (__bf16)0.f; sbB[j] = (__bf16)0.f; }
        } else {
            #pragma unroll
            for (int j = 0; j < 8; ++j) { sbA[j] = (__bf16)0.f; sbB[j] = (__bf16)0.f; }
        }
    }

    // ---- hoisted W3 fragment loads (L2-hot) ----
    long w3r[4][3];
    {
        const long* gw3 = (const long*)w3c;
        #pragma unroll
        for (int q = 0; q < 4; ++q)
            #pragma unroll
            for (int k2 = 0; k2 < 3; ++k2)
                w3r[q][k2] = gw3[(q * 3 + k2) * 64 + ln];
    }

    // ---- Phase A from L2-resident w1p: h1 as MX B-frags + K=32 tail ----
    int8v fmA[3], fmB[3];
    long fr12A, fr12B;
    {
        #pragma unroll
        for (int m = 0; m < 3; ++m)
            #pragma unroll
            for (int j = 0; j < 8; ++j) {
                int nt = m * 8 + j;
                bf16x8 w = *(const bf16x8*)(w1p + (nt * 64 + ln) * 8);
                f32x4 aA = {0.f,0.f,0.f,0.f}, aB = {0.f,0.f,0.f,0.f};
                aA = __builtin_amdgcn_mfma_f32_16x16x32_bf16(w, sbA, aA, 0, 0, 0);
                aB = __builtin_amdgcn_mfma_f32_16x16x32_bf16(w, sbB, aB, 0, 0, 0);
                fmA[m][j] = (int)pkword(lrelu(aA[0]), lrelu(aA[1]), lrelu(aA[2]), lrelu(aA[3]));
                fmB[m][j] = (int)pkword(lrelu(aB[0]), lrelu(aB[1]), lrelu(aB[2]), lrelu(aB[3]));
            }
        unsigned dA[2], dB[2];
        #pragma unroll
        for (int h = 0; h < 2; ++h) {
            int nt = 24 + h;
            bf16x8 w = *(const bf16x8*)(w1p + (nt * 64 + ln) * 8);
            f32x4 aA = {0.f,0.f,0.f,0.f}, aB = {0.f,0.f,0.f,0.f};
            aA = __builtin_amdgcn_mfma_f32_16x16x32_bf16(w, sbA, aA, 0, 0, 0);
            aB = __builtin_amdgcn_mfma_f32_16x16x32_bf16(w, sbB, aB, 0, 0, 0);
            dA[h] = pkword(lrelu(aA[0]), lrelu(aA[1]), lrelu(aA[2]), lrelu(aA[3]));
            dB[h] = pkword(lrelu(aB[0]), lrelu(aB[1]), lrelu(aB[2]), lrelu(aB[3]));
        }
        fr12A = mk64(dA[0], dA[1]);
        fr12B = mk64(dB[0], dB[1]);
    }

    __syncthreads();   // THE barrier: W2 staged & visible; nothing syncs after

    // ---- 4 quarters, fully independent per wave (LDS read-only) ----
    f32x4 ccsA = {0.f, 0.f, 0.f, 0.f};
    f32x4 ccsB = {0.f, 0.f, 0.f, 0.f};

    #pragma unroll 1
    for (int q = 0; q < 4; ++q) {
        const char* bufp = s_w2 + q * 33280;
        unsigned wdA[5], wdB[5];
        #pragma unroll
        for (int t = 0; t < 5; ++t) {
            const char* bt = bufp + t * 6656;
            f32x4 aA = {0.f,0.f,0.f,0.f}, aB = {0.f,0.f,0.f,0.f};
            #pragma unroll
            for (int m = 0; m < 3; ++m) {
                int8v wf = *(const int8v*)(bt + m * 2048 + ln * 32);
                aA = __builtin_amdgcn_mfma_scale_f32_16x16x128_f8f6f4(
                         wf, fmA[m], aA, 0, 0, 0, SCL1, 0, SCL1);
                aB = __builtin_amdgcn_mfma_scale_f32_16x16x128_f8f6f4(
                         wf, fmB[m], aB, 0, 0, 0, SCL1, 0, SCL1);
            }
            long p12 = *(const long*)(bt + 6144 + ln * 8);
            aA = __builtin_amdgcn_mfma_f32_16x16x32_fp8_fp8(p12, fr12A, aA, 0, 0, 0);
            aB = __builtin_amdgcn_mfma_f32_16x16x32_fp8_fp8(p12, fr12B, aB, 0, 0, 0);
            wdA[t] = pkword(lrelu(aA[0]), lrelu(aA[1]), lrelu(aA[2]), lrelu(aA[3]));
            wdB[t] = pkword(lrelu(aB[0]), lrelu(aB[1]), lrelu(aB[2]), lrelu(aB[3]));
        }
        {
            f32x4 cc = {0.f, 0.f, 0.f, 0.f};
            cc = __builtin_amdgcn_mfma_f32_16x16x32_fp8_fp8(w3r[q][0], mk64(wdA[0], wdA[1]), cc, 0, 0, 0);
            cc = __builtin_amdgcn_mfma_f32_16x16x32_fp8_fp8(w3r[q][1], mk64(wdA[2], wdA[3]), cc, 0, 0, 0);
            cc = __builtin_amdgcn_mfma_f32_16x16x32_fp8_fp8(w3r[q][2], mk64(wdA[4], 0u),     cc, 0, 0, 0);
            ccsA += cc;
        }
        {
            f32x4 cc = {0.f, 0.f, 0.f, 0.f};
            cc = __builtin_amdgcn_mfma_f32_16x16x32_fp8_fp8(w3r[q][0], mk64(wdB[0], wdB[1]), cc, 0, 0, 0);
            cc = __builtin_amdgcn_mfma_f32_16x16x32_fp8_fp8(w3r[q][1], mk64(wdB[2], wdB[3]), cc, 0, 0, 0);
            cc = __builtin_amdgcn_mfma_f32_16x16x32_fp8_fp8(w3r[q][2], mk64(wdB[4], 0u),     cc, 0, 0, 0);
            ccsB += cc;
        }
    }

    // ---- Epilogue: 32 lanes/wave solve QP for 32 rows ----
    float tA4 = __shfl_xor(ccsA[0], 16);
    float sB0 = __shfl_xor(ccsB[0], 16);
    float sB1 = __shfl_xor(ccsB[1], 16);
    float sB2 = __shfl_xor(ccsB[2], 16);
    float sB3 = __shfl_xor(ccsB[3], 16);

    if (ln < 32) {
        float v[5];
        if (ln < 16) {
            v[0] = -lrelu(ccsA[0]); v[1] = -lrelu(ccsA[1]);
            v[2] = -lrelu(ccsA[2]); v[3] = -lrelu(ccsA[3]);
            v[4] = -lrelu(tA4);
        } else {
            v[0] = -lrelu(sB0); v[1] = -lrelu(sB1);
            v[2] = -lrelu(sB2); v[3] = -lrelu(sB3);
            v[4] = -lrelu(ccsB[0]);
        }

        float bp[10];
        #pragma unroll
        for (int i = 0; i < 5; ++i) { bp[i] = v[i]; bp[i + 5] = v[i] - UBV; }
        float blo = -1e30f, glo = 0.f;
        #pragma unroll
        for (int j = 0; j < 10; ++j) {
            float b = bp[j];
            float gsum = 0.f;
            #pragma unroll
            for (int i = 0; i < 5; ++i) {
                float zc = v[i] - b;
                zc = fminf(fmaxf(zc, 0.f), UBV);
                gsum += zc;
            }
            if (gsum >= SUMC && b > blo) { blo = b; glo = gsum; }
        }
        float bhi = 1e30f;
        #pragma unroll
        for (int j = 0; j < 10; ++j) {
            float b = bp[j];
            if (b > blo && b < bhi) bhi = b;
        }
        float mid = 0.5f * (blo + bhi);
        int nfree = 0;
        #pragma unroll
        for (int i = 0; i < 5; ++i)
            nfree += (v[i] > mid && v[i] < mid + UBV) ? 1 : 0;
        float nu = (nfree > 0) ? blo + (glo - SUMC) / (float)nfree : blo;

        int row = brow + ln;
        #pragma unroll
        for (int o = 0; o < 5; ++o) {
            float zf = v[o] - nu;
            zf = fminf(fmaxf(zf, 0.f), UBV);
            out[row * 5 + o] = zf;
        }
    }
}

extern "C" void kernel_launch(void* const* d_in, const int* in_sizes, int n_in,
                              void* d_out, int out_size, void* d_ws, size_t ws_size,
                              hipStream_t stream) {
    const float* state = (const float*)d_in[0];
    const float* W1    = (const float*)d_in[1];
    const float* b1    = (const float*)d_in[2];
    const float* W2    = (const float*)d_in[3];
    const float* b2    = (const float*)d_in[4];
    const float* W3    = (const float*)d_in[5];
    const float* b3    = (const float*)d_in[6];
    float* out = (float*)d_out;

    char* base = (char*)d_ws;
    __bf16* w1p = (__bf16*)base;                   // 26,624B
    uint2*  w2p = (uint2*)(base + 26624);          // 133,120B
    uint2*  w3c = (uint2*)(base + 26624 + 133120); // 6,144B

    const int total = 1664 + 16640 + 768;
    prep_kernel<<<(total + 255) / 256, 256, 0, stream>>>(W1, b1, W2, b2, W3, b3,
                                                         w1p, w2p, w3c);

    int B = in_sizes[0] / 17;                      // 65536
    actor_kernel<<<B / 256, 512, 0, stream>>>(state, w1p, w2p, w3c, out);
}